// Round 2
// baseline (137.171 us; speedup 1.0000x reference)
//
#include <hip/hip_runtime.h>
#include <math.h>

typedef _Float16 f16;
typedef __attribute__((ext_vector_type(4))) _Float16 f16x4;
typedef __attribute__((ext_vector_type(8))) _Float16 f16x8;
typedef __attribute__((ext_vector_type(2))) __fp16 h16x2;
typedef __attribute__((ext_vector_type(4))) __fp16 h16x4;
typedef __attribute__((ext_vector_type(4))) float f32x4;
typedef __attribute__((ext_vector_type(16))) float f32x16;

__device__ __forceinline__ void load_lds16(const void* g, void* l) {
    __builtin_amdgcn_global_load_lds((const __attribute__((address_space(1))) void*)g,
                                     (__attribute__((address_space(3))) void*)l, 16, 0, 0);
}

__device__ __forceinline__ float fast_exp2(float x) {
#if __has_builtin(__builtin_amdgcn_exp2f)
    return __builtin_amdgcn_exp2f(x);
#else
    return __exp2f(x);
#endif
}

#define MFMA32(a, b, c) __builtin_amdgcn_mfma_f32_16x16x32_f16(a, b, c, 0, 0, 0)
#define MFMA3216(a, b, c) __builtin_amdgcn_mfma_f32_32x32x16_f16(a, b, c, 0, 0, 0)

// ---------------------------------------------------------------------------
// Kernel 1: x[c][p] fp32 -> xh[p][c] fp16   (c=256, p=4096)
// ---------------------------------------------------------------------------
__global__ __launch_bounds__(256) void kxpose(const float* __restrict__ x,
                                              f16* __restrict__ xh) {
    __shared__ f16 t[64][65];
    const int p0 = blockIdx.x * 64;
    const int c0 = blockIdx.y * 64;
    const int lp = threadIdx.x & 63;
    const int lq = threadIdx.x >> 6;
    for (int i = 0; i < 64; i += 4)
        t[i + lq][lp] = (f16)x[(size_t)(c0 + i + lq) * 4096 + p0 + lp];
    __syncthreads();
    for (int i = 0; i < 64; i += 4)
        xh[(size_t)(p0 + i + lq) * 256 + c0 + lp] = t[lp][i + lq];
}

// ---------------------------------------------------------------------------
// Kernel 2: QKV GEMM, BM=128 BN=64 (grid 64x12 = 768 blocks, 3/CU).
// Epilogues: q/k -> [head][p][d] via single-phase Ts transpose
//            (q pre-scaled 0.125*log2e); v -> [head][d][p] from acc C-layout.
// ---------------------------------------------------------------------------
__global__ __launch_bounds__(256) void gemm_qkv(
        const float* __restrict__ A, const f16* __restrict__ B,
        f16* __restrict__ qb, f16* __restrict__ kb, f16* __restrict__ vb) {
    __shared__ __align__(16) char smem[24576];
    f16* As = (f16*)smem;                  // 128 x 64 = 16 KB
    f16* Bs = (f16*)(smem + 16384);        // 64 x 64 = 8 KB
    const int K = 256, tid = threadIdx.x;
    const int w = tid >> 6, lane = tid & 63, l16 = lane & 15, g = lane >> 4;
    const int wm = w >> 1, wn = w & 1;
    const int mBase = blockIdx.y * 128, nBase = blockIdx.x * 64;
    const int swz = lane & 7;

    f32x4 acc[4][2] = {};
    const int srow = tid >> 1;
    const int sc0 = (tid & 1) * 4;

    for (int k0 = 0; k0 < K; k0 += 64) {
        for (int cc = 0; cc < 4; cc++) {
            const int c = sc0 + cc;
            const float* ap = A + (size_t)(mBase + srow) * K + k0 + c * 8;
            float4 u0 = *(const float4*)ap;
            float4 u1 = *(const float4*)(ap + 4);
            f16x8 hv;
            hv[0] = (f16)u0.x; hv[1] = (f16)u0.y; hv[2] = (f16)u0.z; hv[3] = (f16)u0.w;
            hv[4] = (f16)u1.x; hv[5] = (f16)u1.y; hv[6] = (f16)u1.z; hv[7] = (f16)u1.w;
            *(f16x8*)&As[srow * 64 + ((c ^ (srow & 7)) * 8)] = hv;
        }
        for (int c = 0; c < 2; c++) {
            const int L = c * 256 + w * 64 + lane;
            const int row = L >> 3;
            load_lds16(B + (size_t)(nBase + row) * K + k0 + (((lane & 7) ^ (row & 7)) * 8),
                       &Bs[(c * 256 + w * 64) * 8]);
        }
        __syncthreads();
        for (int ks = 0; ks < 2; ks++) {
            const int ch = ((ks * 4 + g) ^ swz) * 8;
            f16x8 af[4], bf[2];
            for (int t = 0; t < 4; t++)
                af[t] = *(const f16x8*)&As[(wm * 64 + t * 16 + l16) * 64 + ch];
            for (int t = 0; t < 2; t++)
                bf[t] = *(const f16x8*)&Bs[(wn * 32 + t * 16 + l16) * 64 + ch];
            for (int mt = 0; mt < 4; mt++)
                for (int nt = 0; nt < 2; nt++)
                    acc[mt][nt] = MFMA32(af[mt], bf[nt], acc[mt][nt]);
        }
        __syncthreads();
    }

    const int which = mBase >> 9;  // 0=q, 1=k, 2=v (block-uniform)
    if (which == 2) {
        // V: direct from C-layout into [head][d][p]
        for (int mt = 0; mt < 4; mt++)
            for (int nt = 0; nt < 2; nt++)
                for (int r = 0; r < 4; r++) {
                    const int o = mBase + wm * 64 + mt * 16 + g * 4 + r;
                    const int p = nBase + wn * 32 + nt * 16 + l16;
                    const int vd = o - 1024;
                    vb[(size_t)(vd >> 6) * 262144 + (size_t)(vd & 63) * 4096 + p] =
                        (f16)acc[mt][nt][r];
                }
    } else {
        f16* tgt = (which == 0) ? qb : kb;
        const float sc = (which == 0) ? 0.18033688011112042f : 1.0f;  // 0.125*log2e
        f16* Ts = (f16*)smem;  // 64 p-rows x stride-136 = 17408 B
        for (int mt = 0; mt < 4; mt++)
            for (int nt = 0; nt < 2; nt++)
                for (int r = 0; r < 4; r++)
                    Ts[(wn * 32 + nt * 16 + l16) * 136 + wm * 64 + mt * 16 + g * 4 + r] =
                        (f16)(acc[mt][nt][r] * sc);
        __syncthreads();
        const int row = tid >> 2;                 // p_loc 0..63
        const int p = nBase + row;
        for (int cc = 0; cc < 4; cc++) {
            const int c8 = (tid & 3) * 4 + cc;    // 8-f16 chunk of o (0..15)
            f16x8 v = *(const f16x8*)&Ts[row * 136 + c8 * 8];
            const int o = mBase + c8 * 8;
            const int head = (o >> 6) & 7;
            const int d = o & 63;
            *(f16x8*)&tgt[(size_t)head * 262144 + (size_t)p * 64 + d] = v;
        }
    }
}

// ---------------------------------------------------------------------------
// Helper: softmax one 32-wide S half (f32x16 C-regs) -> 2 PV A-fragments.
// ---------------------------------------------------------------------------
__device__ __forceinline__ void soft8(const f32x16 sv, f16x8* pa, float& ls,
                                      const h16x2 one2) {
#pragma unroll
    for (int half = 0; half < 2; half++) {
        h16x2 c0 = __builtin_amdgcn_cvt_pkrtz(fast_exp2(sv[half * 8 + 0]),
                                              fast_exp2(sv[half * 8 + 1]));
        h16x2 c1 = __builtin_amdgcn_cvt_pkrtz(fast_exp2(sv[half * 8 + 2]),
                                              fast_exp2(sv[half * 8 + 3]));
        h16x2 c2 = __builtin_amdgcn_cvt_pkrtz(fast_exp2(sv[half * 8 + 4]),
                                              fast_exp2(sv[half * 8 + 5]));
        h16x2 c3 = __builtin_amdgcn_cvt_pkrtz(fast_exp2(sv[half * 8 + 6]),
                                              fast_exp2(sv[half * 8 + 7]));
        ls = __builtin_amdgcn_fdot2(c0, one2, ls, false);
        ls = __builtin_amdgcn_fdot2(c1, one2, ls, false);
        ls = __builtin_amdgcn_fdot2(c2, one2, ls, false);
        ls = __builtin_amdgcn_fdot2(c3, one2, ls, false);
        h16x4 plo = __builtin_shufflevector(c0, c1, 0, 1, 2, 3);
        h16x4 phi = __builtin_shufflevector(c2, c3, 0, 1, 2, 3);
        pa[half] = __builtin_bit_cast(
            f16x8, __builtin_shufflevector(plo, phi, 0, 1, 2, 3, 4, 5, 6, 7));
    }
}

// ---------------------------------------------------------------------------
// Kernel 3: flash attention, 32x32x16 MFMA, interleaved 2-tile schedule.
// grid 1024 = 8h x 32it x 4s; 128 i-rows/block, 32 i-rows/wave.
// K rows staged permuted so QK C-regs ARE the PV A-fragments (no LDS P).
// Schedule per jt: prefetch | QK0+QK1 (8 MFMA queued) | soft0 | PV0 |
//                  V1 loads | barrier | soft1 | PV1  -- softmax overlaps
// MFMA pipe; barrier latency hides under register-only soft1+PV1.
// ---------------------------------------------------------------------------
__global__ __launch_bounds__(256, 3) void attn_fwd(
        const f16* __restrict__ qb, const f16* __restrict__ kb,
        const f16* __restrict__ vb, f16* __restrict__ Op, float* __restrict__ Lp) {
    __shared__ __align__(16) char smem[32768];
    f16* Ks = (f16*)smem;                  // 2 x 8KB double buffer (row-permuted)
    f16* Vs = (f16*)(smem + 16384);        // 2 x 8KB double buffer
    const int tid = threadIdx.x;
    const int w = tid >> 6, lane = tid & 63, l31 = lane & 31, hi = lane >> 5;
    const int bx = blockIdx.x;
    const int h = bx & 7, rest = bx >> 3, it = rest >> 2, s = rest & 3;
    const f16* Qw = qb + (size_t)h * 262144 + (size_t)(it * 128 + w * 32) * 64;
    const f16* Kh = kb + (size_t)h * 262144 + (size_t)s * 65536;   // [j][d]
    const f16* Vh = vb + (size_t)h * 262144 + (size_t)s * 1024;    // [d][j]

    // staging offsets; K source rows permuted within 16-row groups
    const int L0 = w * 64 + lane, L1 = 256 + L0;
    const int r0 = L0 >> 3, r1 = L1 >> 3;
    const int q0 = (r0 >> 2) & 3, q1 = (r1 >> 2) & 3;
    const int rg0 = r0 + ((q0 == 1) ? 4 : (q0 == 2) ? -4 : 0);
    const int rg1 = r1 + ((q1 == 1) ? 4 : (q1 == 2) ? -4 : 0);
    const int kO0 = rg0 * 64 + (((L0 & 7) ^ (r0 & 7)) * 8);
    const int kO1 = rg1 * 64 + (((L1 & 7) ^ (r1 & 7)) * 8);
    const int vO0 = r0 * 4096 + (((L0 & 7) ^ (r0 & 7)) * 8);
    const int vO1 = r1 * 4096 + (((L1 & 7) ^ (r1 & 7)) * 8);

    load_lds16(Kh + kO0, &Ks[L0 * 8]);
    load_lds16(Kh + kO1, &Ks[L1 * 8]);
    load_lds16(Vh + vO0, &Vs[L0 * 8]);
    load_lds16(Vh + vO1, &Vs[L1 * 8]);

    // Q B-fragments: col = i = l31, k = ks*16 + hi*8 + e
    f16x8 qf[4];
#pragma unroll
    for (int ks = 0; ks < 4; ks++)
        qf[ks] = *(const f16x8*)(Qw + l31 * 64 + ks * 16 + hi * 8);

    __syncthreads();

    f32x16 oacc[2] = {};
    float lsumA = 0.f, lsumB = 0.f;
    const h16x2 one2 = {(__fp16)1.0f, (__fp16)1.0f};
    const int rk = l31 & 7;
    const f16* KbA = Ks + l31 * 64;          // jt2=0 rows (+cur*4096)
    const f16* KbB = Ks + (32 + l31) * 64;   // jt2=1 rows
    const f16* VbA = Vs + l31 * 64;          // dt=0 (d 0..31)
    const f16* VbB = Vs + (32 + l31) * 64;   // dt=1 (d 32..63)

#pragma unroll
    for (int jt = 0; jt < 16; jt++) {
        const int cur = jt & 1;
        if (jt < 15) {
            const int nxt = cur ^ 1;
            const f16* Kt = Kh + (jt + 1) * 4096;
            const f16* Vt = Vh + (jt + 1) * 64;
            load_lds16(Kt + kO0, &Ks[nxt * 4096 + L0 * 8]);
            load_lds16(Kt + kO1, &Ks[nxt * 4096 + L1 * 8]);
            load_lds16(Vt + vO0, &Vs[nxt * 4096 + L0 * 8]);
            load_lds16(Vt + vO1, &Vs[nxt * 4096 + L1 * 8]);
        }
        const int co = cur * 4096;
        // --- both QK halves: 8 MFMAs queued back-to-back ---
        f32x16 sv0 = {}, sv1 = {};
        __builtin_amdgcn_s_setprio(1);
#pragma unroll
        for (int ks = 0; ks < 4; ks++) {
            f16x8 kf0 = *(const f16x8*)(KbA + co + (((ks * 2 + hi) ^ rk) * 8));
            f16x8 kf1 = *(const f16x8*)(KbB + co + (((ks * 2 + hi) ^ rk) * 8));
            sv0 = MFMA3216(kf0, qf[ks], sv0);
            sv1 = MFMA3216(kf1, qf[ks], sv1);
        }
        __builtin_amdgcn_s_setprio(0);
        // --- softmax half 0 (overlaps QK pipe) ---
        f16x8 pa0[2];
        soft8(sv0, pa0, lsumA, one2);
        // --- PV half 0 ---
        f16x8 bv00 = *(const f16x8*)(VbA + co + (((0 + hi) ^ rk) * 8));
        f16x8 bv01 = *(const f16x8*)(VbA + co + (((2 + hi) ^ rk) * 8));
        f16x8 bv10 = *(const f16x8*)(VbB + co + (((0 + hi) ^ rk) * 8));
        f16x8 bv11 = *(const f16x8*)(VbB + co + (((2 + hi) ^ rk) * 8));
        __builtin_amdgcn_s_setprio(1);
        oacc[0] = MFMA3216(pa0[0], bv00, oacc[0]);
        oacc[0] = MFMA3216(pa0[1], bv01, oacc[0]);
        oacc[1] = MFMA3216(pa0[0], bv10, oacc[1]);
        oacc[1] = MFMA3216(pa0[1], bv11, oacc[1]);
        __builtin_amdgcn_s_setprio(0);
        // --- last LDS reads of cur buffer, then barrier early ---
        f16x8 cv00 = *(const f16x8*)(VbA + co + (((4 + hi) ^ rk) * 8));
        f16x8 cv01 = *(const f16x8*)(VbA + co + (((6 + hi) ^ rk) * 8));
        f16x8 cv10 = *(const f16x8*)(VbB + co + (((4 + hi) ^ rk) * 8));
        f16x8 cv11 = *(const f16x8*)(VbB + co + (((6 + hi) ^ rk) * 8));
        __syncthreads();
        // --- softmax half 1 + PV half 1 (register-only, hides barrier) ---
        f16x8 pa1[2];
        soft8(sv1, pa1, lsumB, one2);
        __builtin_amdgcn_s_setprio(1);
        oacc[0] = MFMA3216(pa1[0], cv00, oacc[0]);
        oacc[0] = MFMA3216(pa1[1], cv01, oacc[0]);
        oacc[1] = MFMA3216(pa1[0], cv10, oacc[1]);
        oacc[1] = MFMA3216(pa1[1], cv11, oacc[1]);
        __builtin_amdgcn_s_setprio(0);
    }

    float lsum = lsumA + lsumB;
    lsum += __shfl_xor(lsum, 32);
    if (lane < 32)
        Lp[(size_t)s * 32768 + (size_t)(it * 128 + w * 32 + lane) * 8 + h] = lsum;
    f16* Oh = Op + (size_t)s * 2097152 + (size_t)(it * 128 + w * 32) * 512 + h * 64;
#pragma unroll
    for (int dt = 0; dt < 2; dt++)
#pragma unroll
        for (int r = 0; r < 16; r++) {
            const int i = (r & 3) + 8 * (r >> 2) + 4 * hi;
            Oh[(size_t)i * 512 + dt * 32 + l31] = (f16)oacc[dt][r];
        }
}

// ---------------------------------------------------------------------------
// Kernel 4: out GEMM with fused combine, BM=64 BN=32, grid (128,4) = 512 blocks.
// ---------------------------------------------------------------------------
__global__ __launch_bounds__(256) void gemm_out(
        const float* __restrict__ A, const f16* __restrict__ Op,
        const float* __restrict__ Lp, const float* __restrict__ bias,
        float* __restrict__ C) {
    __shared__ __align__(16) char smem[13312];
    f16* As = (f16*)smem;                  // 64 x 64 = 8 KB
    f16* Bs = (f16*)(smem + 8192);         // 32 x 64 = 4 KB
    float* invL = (float*)(smem + 12288);  // 32 p x 8 h
    const int tid = threadIdx.x;
    const int w = tid >> 6, lane = tid & 63, l16 = lane & 15, g = lane >> 4;
    const int wm = w >> 1, wn = w & 1;
    const int mBase = blockIdx.y * 64, nBase = blockIdx.x * 32;
    const int swz = lane & 7;

    {
        const int idx = tid;                   // p_loc*8 + h  (256 entries)
        const int p = nBase + (idx >> 3), hh = idx & 7;
        float sum = 0.f;
        for (int s4 = 0; s4 < 4; s4++) sum += Lp[(size_t)s4 * 32768 + p * 8 + hh];
        invL[idx] = 1.0f / sum;
    }
    __syncthreads();

    f32x4 acc[2][1] = {};
    const int srow = tid >> 2;
    const int sc0 = (tid & 3) * 2;

    for (int k0 = 0; k0 < 512; k0 += 64) {
        for (int cc = 0; cc < 2; cc++) {
            const int c = sc0 + cc;
            const float* ap = A + (size_t)(mBase + srow) * 512 + k0 + c * 8;
            float4 u0 = *(const float4*)ap;
            float4 u1 = *(const float4*)(ap + 4);
            f16x8 hv;
            hv[0] = (f16)u0.x; hv[1] = (f16)u0.y; hv[2] = (f16)u0.z; hv[3] = (f16)u0.w;
            hv[4] = (f16)u1.x; hv[5] = (f16)u1.y; hv[6] = (f16)u1.z; hv[7] = (f16)u1.w;
            *(f16x8*)&As[srow * 64 + ((c ^ (srow & 7)) * 8)] = hv;
        }
        const int hk = k0 >> 6;               // head for this k-tile (uniform)
        {
            const int L = tid;                 // 32 rows x 8 chunks = 256
            const int row = L >> 3, ch = L & 7;
            const int gc = ch ^ (row & 7);
            const f16* op0 = Op + (size_t)(nBase + row) * 512 + k0 + gc * 8;
            f16x8 b0 = *(const f16x8*)(op0);
            f16x8 b1 = *(const f16x8*)(op0 + 2097152);
            f16x8 b2 = *(const f16x8*)(op0 + 4194304);
            f16x8 b3 = *(const f16x8*)(op0 + 6291456);
            const f16 iv = (f16)invL[row * 8 + hk];
            f16x8 bsum = (b0 + b1) + (b2 + b3);
            bsum = bsum * iv;
            *(f16x8*)&Bs[L * 8] = bsum;
        }
        __syncthreads();
        for (int ks = 0; ks < 2; ks++) {
            const int chv = ((ks * 4 + g) ^ swz) * 8;
            f16x8 af[2], bf;
            for (int t = 0; t < 2; t++)
                af[t] = *(const f16x8*)&As[(wm * 32 + t * 16 + l16) * 64 + chv];
            bf = *(const f16x8*)&Bs[(wn * 16 + l16) * 64 + chv];
            for (int mt = 0; mt < 2; mt++)
                acc[mt][0] = MFMA32(af[mt], bf, acc[mt][0]);
        }
        __syncthreads();
    }

    for (int mt = 0; mt < 2; mt++)
        for (int r = 0; r < 4; r++) {
            const int o = mBase + wm * 32 + mt * 16 + g * 4 + r;
            const float bb = bias[o];
            const int p = nBase + wn * 16 + l16;
            C[(size_t)o * 4096 + p] = acc[mt][0][r] + bb;
        }
}

// ---------------------------------------------------------------------------
extern "C" void kernel_launch(void* const* d_in, const int* in_sizes, int n_in,
                              void* d_out, int out_size, void* d_ws, size_t ws_size,
                              hipStream_t stream) {
    const float* x    = (const float*)d_in[0];  // (1,256,64,64)
    const float* wqkv = (const float*)d_in[1];  // (1536,256)
    const float* wout = (const float*)d_in[2];  // (256,512)
    const float* bout = (const float*)d_in[3];  // (256,)
    float* out = (float*)d_out;                 // (1,256,64,64)

    char* ws = (char*)d_ws;
    float* Lp = (float*)(ws);                    // [0,512K) written by attn
    f16* qb = (f16*)(ws + (2u << 20));           // [2M,6M)
    f16* kb = (f16*)(ws + (6u << 20));           // [6M,10M)
    f16* vb = (f16*)(ws + (10u << 20));          // [10M,14M) [head][d][p]
    f16* Op = (f16*)(ws + (14u << 20));          // [14M,30M) 4 split quarters
    f16* xh = (f16*)(ws + (30u << 20));          // [30M,32M) transposed x

    kxpose<<<dim3(64, 4), 256, 0, stream>>>(x, xh);
    gemm_qkv<<<dim3(64, 12), 256, 0, stream>>>(wqkv, xh, qb, kb, vb);
    attn_fwd<<<dim3(1024), 256, 0, stream>>>(qb, kb, vb, Op, Lp);
    gemm_out<<<dim3(128, 4), 256, 0, stream>>>(wout, Op, Lp, bout, out);
}

// Round 3
// 131.885 us; speedup vs baseline: 1.0401x; 1.0401x over previous
//
#include <hip/hip_runtime.h>
#include <math.h>

typedef _Float16 f16;
typedef __attribute__((ext_vector_type(4))) _Float16 f16x4;
typedef __attribute__((ext_vector_type(8))) _Float16 f16x8;
typedef __attribute__((ext_vector_type(2))) __fp16 h16x2;
typedef __attribute__((ext_vector_type(4))) __fp16 h16x4;
typedef __attribute__((ext_vector_type(4))) float f32x4;
typedef __attribute__((ext_vector_type(16))) float f32x16;

__device__ __forceinline__ void load_lds16(const void* g, void* l) {
    __builtin_amdgcn_global_load_lds((const __attribute__((address_space(1))) void*)g,
                                     (__attribute__((address_space(3))) void*)l, 16, 0, 0);
}

__device__ __forceinline__ float fast_exp2(float x) {
#if __has_builtin(__builtin_amdgcn_exp2f)
    return __builtin_amdgcn_exp2f(x);
#else
    return __exp2f(x);
#endif
}

#define MFMA32(a, b, c) __builtin_amdgcn_mfma_f32_16x16x32_f16(a, b, c, 0, 0, 0)
#define MFMA3216(a, b, c) __builtin_amdgcn_mfma_f32_32x32x16_f16(a, b, c, 0, 0, 0)

// ---------------------------------------------------------------------------
// Kernel 1: x[c][p] fp32 -> xh[p][c] fp16   (c=256, p=4096)
// ---------------------------------------------------------------------------
__global__ __launch_bounds__(256) void kxpose(const float* __restrict__ x,
                                              f16* __restrict__ xh) {
    __shared__ f16 t[64][65];
    const int p0 = blockIdx.x * 64;
    const int c0 = blockIdx.y * 64;
    const int lp = threadIdx.x & 63;
    const int lq = threadIdx.x >> 6;
    for (int i = 0; i < 64; i += 4)
        t[i + lq][lp] = (f16)x[(size_t)(c0 + i + lq) * 4096 + p0 + lp];
    __syncthreads();
    for (int i = 0; i < 64; i += 4)
        xh[(size_t)(p0 + i + lq) * 256 + c0 + lp] = t[lp][i + lq];
}

// ---------------------------------------------------------------------------
// Kernel 2: QKV GEMM, BM=BN=128 (grid 32x12), B via global_load_lds from xh.
// Epilogues: q -> [head][p][d]; k -> [head][dchunk][j][8] (chunk-major for
// attn staging); v -> [head][jchunk][d][8]. q pre-scaled 0.125*log2e.
// ---------------------------------------------------------------------------
__global__ __launch_bounds__(256) void gemm_qkv(
        const float* __restrict__ A, const f16* __restrict__ B,
        f16* __restrict__ qb, f16* __restrict__ kb, f16* __restrict__ vb) {
    __shared__ __align__(16) char smem[32768];
    f16* As = (f16*)smem;
    f16* Bs = (f16*)(smem + 16384);
    const int K = 256, tid = threadIdx.x;
    const int w = tid >> 6, lane = tid & 63, l16 = lane & 15, g = lane >> 4;
    const int wm = w >> 1, wn = w & 1;
    const int mBase = blockIdx.y * 128, nBase = blockIdx.x * 128;
    const int swz = lane & 7;

    f32x4 acc[4][4] = {};
    const int srow = tid >> 1;
    const int sc0 = (tid & 1) * 4;

    for (int k0 = 0; k0 < K; k0 += 64) {
        for (int cc = 0; cc < 4; cc++) {
            const int c = sc0 + cc;
            const float* ap = A + (size_t)(mBase + srow) * K + k0 + c * 8;
            float4 u0 = *(const float4*)ap;
            float4 u1 = *(const float4*)(ap + 4);
            f16x8 hv;
            hv[0] = (f16)u0.x; hv[1] = (f16)u0.y; hv[2] = (f16)u0.z; hv[3] = (f16)u0.w;
            hv[4] = (f16)u1.x; hv[5] = (f16)u1.y; hv[6] = (f16)u1.z; hv[7] = (f16)u1.w;
            *(f16x8*)&As[srow * 64 + ((c ^ (srow & 7)) * 8)] = hv;
        }
        for (int c = 0; c < 4; c++) {
            const int L = c * 256 + w * 64 + lane;
            const int row = L >> 3;
            load_lds16(B + (size_t)(nBase + row) * K + k0 + (((lane & 7) ^ (row & 7)) * 8),
                       &Bs[(c * 256 + w * 64) * 8]);
        }
        __syncthreads();
        for (int ks = 0; ks < 2; ks++) {
            const int ch = ((ks * 4 + g) ^ swz) * 8;
            f16x8 af[4], bf[4];
            for (int t = 0; t < 4; t++)
                af[t] = *(const f16x8*)&As[(wm * 64 + t * 16 + l16) * 64 + ch];
            for (int t = 0; t < 4; t++)
                bf[t] = *(const f16x8*)&Bs[(wn * 64 + t * 16 + l16) * 64 + ch];
            for (int mt = 0; mt < 4; mt++)
                for (int nt = 0; nt < 4; nt++)
                    acc[mt][nt] = MFMA32(af[mt], bf[nt], acc[mt][nt]);
        }
        __syncthreads();
    }

    const int which = mBase >> 9;  // 0=q, 1=k, 2=v (block-uniform)
    if (which == 2) {
        // V: direct from C-layout into [head][jchunk][d][8]
        for (int mt = 0; mt < 4; mt++)
            for (int nt = 0; nt < 4; nt++)
                for (int r = 0; r < 4; r++) {
                    const int o = mBase + wm * 64 + mt * 16 + g * 4 + r;
                    const int p = nBase + wn * 64 + nt * 16 + l16;
                    const int vd = o - 1024;
                    vb[(size_t)(vd >> 6) * 262144 + (size_t)(p >> 3) * 512 +
                       (size_t)(vd & 63) * 8 + (p & 7)] = (f16)acc[mt][nt][r];
                }
    } else {
        const float sc = (which == 0) ? 0.18033688011112042f : 1.0f;  // 0.125*log2e
        f16* Ts = (f16*)smem;  // 64 x stride-136 = 17408 B
        for (int ph = 0; ph < 2; ph++) {
            __syncthreads();
            if (wn == ph) {
                for (int mt = 0; mt < 4; mt++)
                    for (int nt = 0; nt < 4; nt++)
                        for (int r = 0; r < 4; r++)
                            Ts[(nt * 16 + l16) * 136 + wm * 64 + mt * 16 + g * 4 + r] =
                                (f16)(acc[mt][nt][r] * sc);
            }
            __syncthreads();
            const int row = tid >> 2;                 // p within half
            const int p = nBase + ph * 64 + row;
            for (int cc = 0; cc < 4; cc++) {
                const int c8 = (tid & 3) * 4 + cc;    // 8-f16 chunk of o
                f16x8 v = *(const f16x8*)&Ts[row * 136 + c8 * 8];
                const int o = mBase + c8 * 8;
                const int head = (o >> 6) & 7;
                const int d = o & 63;
                if (which == 0)
                    *(f16x8*)&qb[(size_t)head * 262144 + (size_t)p * 64 + d] = v;
                else
                    *(f16x8*)&kb[(size_t)head * 262144 + (size_t)(d >> 3) * 32768 +
                                 (size_t)p * 8] = v;
            }
        }
    }
}

// ---------------------------------------------------------------------------
// Helper: softmax one 32-wide S half (f32x16 C-regs) -> 2 PV A-fragments.
// ---------------------------------------------------------------------------
__device__ __forceinline__ void soft8(const f32x16 sv, f16x8* pa, float& ls,
                                      const h16x2 one2) {
#pragma unroll
    for (int half = 0; half < 2; half++) {
        h16x2 c0 = __builtin_amdgcn_cvt_pkrtz(fast_exp2(sv[half * 8 + 0]),
                                              fast_exp2(sv[half * 8 + 1]));
        h16x2 c1 = __builtin_amdgcn_cvt_pkrtz(fast_exp2(sv[half * 8 + 2]),
                                              fast_exp2(sv[half * 8 + 3]));
        h16x2 c2 = __builtin_amdgcn_cvt_pkrtz(fast_exp2(sv[half * 8 + 4]),
                                              fast_exp2(sv[half * 8 + 5]));
        h16x2 c3 = __builtin_amdgcn_cvt_pkrtz(fast_exp2(sv[half * 8 + 6]),
                                              fast_exp2(sv[half * 8 + 7]));
        ls = __builtin_amdgcn_fdot2(c0, one2, ls, false);
        ls = __builtin_amdgcn_fdot2(c1, one2, ls, false);
        ls = __builtin_amdgcn_fdot2(c2, one2, ls, false);
        ls = __builtin_amdgcn_fdot2(c3, one2, ls, false);
        h16x4 plo = __builtin_shufflevector(c0, c1, 0, 1, 2, 3);
        h16x4 phi = __builtin_shufflevector(c2, c3, 0, 1, 2, 3);
        pa[half] = __builtin_bit_cast(
            f16x8, __builtin_shufflevector(plo, phi, 0, 1, 2, 3, 4, 5, 6, 7));
    }
}

// ---------------------------------------------------------------------------
// Kernel 3: flash attention. 64 i-rows/wave, 256/block; grid 512 = 8h x 16it
// x 4s (2 blocks/CU resident). LDS chunk-major: Ks [dchunk][row][8],
// Vs [jchunk][d][8] -- every frag read is two contiguous 512B half-wave
// blocks (bank-conflict-free), staged coalesced from the chunk-major global
// layouts. K rows staged with the quartet permutation so QK C-regs feed PV A
// directly. Each K/V frag read now feeds 2x MFMAs (两 i-halves) -> LDS read
// traffic per FLOP halved vs the 32-row version.
// ---------------------------------------------------------------------------
__global__ __launch_bounds__(256, 2) void attn_fwd(
        const f16* __restrict__ qb, const f16* __restrict__ kb,
        const f16* __restrict__ vb, f16* __restrict__ Op, float* __restrict__ Lp) {
    __shared__ __align__(16) char smem[32768];
    f16* Ks = (f16*)smem;                  // 2 x 8KB: [c 0..7][row 0..63][8]
    f16* Vs = (f16*)(smem + 16384);        // 2 x 8KB: [jc 0..7][d 0..63][8]
    const int tid = threadIdx.x;
    const int w = tid >> 6, lane = tid & 63, l31 = lane & 31, hi = lane >> 5;
    const int bx = blockIdx.x;
    const int h = bx & 7, rest = bx >> 3, it = rest >> 2, s = rest & 3;
    const f16* Qw = qb + (size_t)h * 262144 + (size_t)(it * 256 + w * 64) * 64;
    const f16* Kh = kb + (size_t)h * 262144;   // [dchunk 8][j 4096][8]
    const f16* Vh = vb + (size_t)h * 262144;   // [jchunk 512][d 64][8]

    // K row permutation within 16-groups: swap quartets 1<->2
    const int q = (lane >> 2) & 3;
    const int rg = lane + ((q == 1) ? 4 : (q == 2) ? -4 : 0);

    const int c0 = w * 2, c1 = w * 2 + 1;
    const f16* kS0 = Kh + (size_t)c0 * 32768 + (size_t)(s * 1024 + rg) * 8;
    const f16* kS1 = Kh + (size_t)c1 * 32768 + (size_t)(s * 1024 + rg) * 8;
    const f16* vS0 = Vh + (size_t)(s * 128 + c0) * 512 + lane * 8;
    const f16* vS1 = Vh + (size_t)(s * 128 + c1) * 512 + lane * 8;

    // stage jt=0 into buffer 0
    load_lds16(kS0, &Ks[c0 * 512]);
    load_lds16(kS1, &Ks[c1 * 512]);
    load_lds16(vS0, &Vs[c0 * 512]);
    load_lds16(vS1, &Vs[c1 * 512]);

    // Q B-fragments: col = i = mi*32 + l31, k = ks*16 + hi*8 + e
    f16x8 qf[2][4];
#pragma unroll
    for (int mi = 0; mi < 2; mi++)
#pragma unroll
        for (int ks = 0; ks < 4; ks++)
            qf[mi][ks] = *(const f16x8*)(Qw + (mi * 32 + l31) * 64 + ks * 16 + hi * 8);

    __syncthreads();

    f32x16 oacc[2][2] = {};
    float lsum[2] = {0.f, 0.f};
    const h16x2 one2 = {(__fp16)1.0f, (__fp16)1.0f};

#pragma unroll 4
    for (int jt = 0; jt < 16; jt++) {
        const int cur = jt & 1;
        if (jt < 15) {
            const int nxt = cur ^ 1;
            load_lds16(kS0 + (jt + 1) * 512, &Ks[nxt * 4096 + c0 * 512]);
            load_lds16(kS1 + (jt + 1) * 512, &Ks[nxt * 4096 + c1 * 512]);
            load_lds16(vS0 + (jt + 1) * 4096, &Vs[nxt * 4096 + c0 * 512]);
            load_lds16(vS1 + (jt + 1) * 4096, &Vs[nxt * 4096 + c1 * 512]);
        }
        const int co = cur * 4096;
#pragma unroll
        for (int jt2 = 0; jt2 < 2; jt2++) {
            // QK fragments: chunk = ks*2+hi, row = jt2*32 + l31
            f16x8 kf[4];
#pragma unroll
            for (int ks = 0; ks < 4; ks++)
                kf[ks] = *(const f16x8*)&Ks[co + (ks * 2 + hi) * 512 +
                                            (jt2 * 32 + l31) * 8];
            f32x16 sv0 = {}, sv1 = {};
            __builtin_amdgcn_s_setprio(1);
#pragma unroll
            for (int ks = 0; ks < 4; ks++) {
                sv0 = MFMA3216(kf[ks], qf[0][ks], sv0);
                sv1 = MFMA3216(kf[ks], qf[1][ks], sv1);
            }
            __builtin_amdgcn_s_setprio(0);
            // V fragments (issued before softmax so ds_reads overlap VALU)
            f16x8 bv[2][2];
#pragma unroll
            for (int ks2 = 0; ks2 < 2; ks2++)
#pragma unroll
                for (int dt = 0; dt < 2; dt++)
                    bv[ks2][dt] = *(const f16x8*)&Vs[co + (jt2 * 4 + ks2 * 2 + hi) * 512 +
                                                     (dt * 32 + l31) * 8];
            f16x8 pa0[2], pa1[2];
            soft8(sv0, pa0, lsum[0], one2);
            soft8(sv1, pa1, lsum[1], one2);
            __builtin_amdgcn_s_setprio(1);
#pragma unroll
            for (int ks2 = 0; ks2 < 2; ks2++)
#pragma unroll
                for (int dt = 0; dt < 2; dt++) {
                    oacc[0][dt] = MFMA3216(pa0[ks2], bv[ks2][dt], oacc[0][dt]);
                    oacc[1][dt] = MFMA3216(pa1[ks2], bv[ks2][dt], oacc[1][dt]);
                }
            __builtin_amdgcn_s_setprio(0);
        }
        __syncthreads();
    }

#pragma unroll
    for (int mi = 0; mi < 2; mi++) {
        float ls = lsum[mi];
        ls += __shfl_xor(ls, 32);
        if (lane < 32)
            Lp[(size_t)s * 32768 +
               (size_t)(it * 256 + w * 64 + mi * 32 + lane) * 8 + h] = ls;
    }
    f16* Oh = Op + (size_t)s * 2097152 + (size_t)(it * 256 + w * 64) * 512 + h * 64;
#pragma unroll
    for (int mi = 0; mi < 2; mi++)
#pragma unroll
        for (int dt = 0; dt < 2; dt++)
#pragma unroll
            for (int r = 0; r < 16; r++) {
                const int i = mi * 32 + (r & 3) + 8 * (r >> 2) + 4 * hi;
                Oh[(size_t)i * 512 + dt * 32 + l31] = (f16)oacc[mi][dt][r];
            }
}

// ---------------------------------------------------------------------------
// Kernel 4: out GEMM with fused combine, BM=BN=64, grid (64,4).
// ---------------------------------------------------------------------------
__global__ __launch_bounds__(256) void gemm_out(
        const float* __restrict__ A, const f16* __restrict__ Op,
        const float* __restrict__ Lp, const float* __restrict__ bias,
        float* __restrict__ C) {
    __shared__ __align__(16) char smem[18432];
    f16* As = (f16*)smem;                  // 8 KB
    f16* Bs = (f16*)(smem + 8192);         // 8 KB
    float* invL = (float*)(smem + 16384);  // 64 p x 8 h
    const int tid = threadIdx.x;
    const int w = tid >> 6, lane = tid & 63, l16 = lane & 15, g = lane >> 4;
    const int wm = w >> 1, wn = w & 1;
    const int mBase = blockIdx.y * 64, nBase = blockIdx.x * 64;
    const int swz = lane & 7;

    for (int e = 0; e < 2; e++) {
        const int idx = tid * 2 + e;           // p_loc*8 + h
        const int p = nBase + (idx >> 3), hh = idx & 7;
        float sum = 0.f;
        for (int s4 = 0; s4 < 4; s4++) sum += Lp[(size_t)s4 * 32768 + p * 8 + hh];
        invL[idx] = 1.0f / sum;
    }
    __syncthreads();

    f32x4 acc[2][2] = {};
    const int srow = tid >> 2;
    const int sc0 = (tid & 3) * 2;

    for (int k0 = 0; k0 < 512; k0 += 64) {
        for (int cc = 0; cc < 2; cc++) {
            const int c = sc0 + cc;
            const float* ap = A + (size_t)(mBase + srow) * 512 + k0 + c * 8;
            float4 u0 = *(const float4*)ap;
            float4 u1 = *(const float4*)(ap + 4);
            f16x8 hv;
            hv[0] = (f16)u0.x; hv[1] = (f16)u0.y; hv[2] = (f16)u0.z; hv[3] = (f16)u0.w;
            hv[4] = (f16)u1.x; hv[5] = (f16)u1.y; hv[6] = (f16)u1.z; hv[7] = (f16)u1.w;
            *(f16x8*)&As[srow * 64 + ((c ^ (srow & 7)) * 8)] = hv;
        }
        const int hk = k0 >> 6;               // head for this k-tile (uniform)
        for (int c = 0; c < 2; c++) {
            const int L = c * 256 + tid;
            const int row = L >> 3, ch = L & 7;
            const int gc = ch ^ (row & 7);
            const f16* op0 = Op + (size_t)(nBase + row) * 512 + k0 + gc * 8;
            f16x8 b0 = *(const f16x8*)(op0);
            f16x8 b1 = *(const f16x8*)(op0 + 2097152);
            f16x8 b2 = *(const f16x8*)(op0 + 4194304);
            f16x8 b3 = *(const f16x8*)(op0 + 6291456);
            const f16 iv = (f16)invL[row * 8 + hk];
            f16x8 bsum = (b0 + b1) + (b2 + b3);
            bsum = bsum * iv;
            *(f16x8*)&Bs[L * 8] = bsum;
        }
        __syncthreads();
        for (int ks = 0; ks < 2; ks++) {
            const int chv = ((ks * 4 + g) ^ swz) * 8;
            f16x8 af[2], bf[2];
            for (int t = 0; t < 2; t++)
                af[t] = *(const f16x8*)&As[(wm * 32 + t * 16 + l16) * 64 + chv];
            for (int t = 0; t < 2; t++)
                bf[t] = *(const f16x8*)&Bs[(wn * 32 + t * 16 + l16) * 64 + chv];
            for (int mt = 0; mt < 2; mt++)
                for (int nt = 0; nt < 2; nt++)
                    acc[mt][nt] = MFMA32(af[mt], bf[nt], acc[mt][nt]);
        }
        __syncthreads();
    }

    for (int mt = 0; mt < 2; mt++)
        for (int r = 0; r < 4; r++) {
            const int o = mBase + wm * 32 + mt * 16 + g * 4 + r;
            const float bb = bias[o];
            for (int nt = 0; nt < 2; nt++) {
                const int p = nBase + wn * 32 + nt * 16 + l16;
                C[(size_t)o * 4096 + p] = acc[mt][nt][r] + bb;
            }
        }
}

// ---------------------------------------------------------------------------
extern "C" void kernel_launch(void* const* d_in, const int* in_sizes, int n_in,
                              void* d_out, int out_size, void* d_ws, size_t ws_size,
                              hipStream_t stream) {
    const float* x    = (const float*)d_in[0];  // (1,256,64,64)
    const float* wqkv = (const float*)d_in[1];  // (1536,256)
    const float* wout = (const float*)d_in[2];  // (256,512)
    const float* bout = (const float*)d_in[3];  // (256,)
    float* out = (float*)d_out;                 // (1,256,64,64)

    char* ws = (char*)d_ws;
    float* Lp = (float*)(ws);                    // [0,512K) written by attn
    f16* qb = (f16*)(ws + (2u << 20));           // [2M,6M)  [head][p][d]
    f16* kb = (f16*)(ws + (6u << 20));           // [6M,10M) [head][dchunk][j][8]
    f16* vb = (f16*)(ws + (10u << 20));          // [10M,14M) [head][jchunk][d][8]
    f16* Op = (f16*)(ws + (14u << 20));          // [14M,30M) 4 split quarters
    f16* xh = (f16*)(ws + (30u << 20));          // [30M,32M) transposed x

    kxpose<<<dim3(64, 4), 256, 0, stream>>>(x, xh);
    gemm_qkv<<<dim3(32, 12), 256, 0, stream>>>(wqkv, xh, qb, kb, vb);
    attn_fwd<<<dim3(512), 256, 0, stream>>>(qb, kb, vb, Op, Lp);
    gemm_out<<<dim3(64, 4), 256, 0, stream>>>(wout, Op, Lp, bout, out);
}